// Round 5
// baseline (33.274 us; speedup 1.0000x reference)
//
#include <hip/hip_runtime.h>
#include <math.h>

// Problem geometry (fixed by the reference setup)
#define CH       48
#define DIM      64
#define SPATIAL  (DIM * DIM * DIM)   // 262144 per (b, c)
#define NB       2
#define VOL      (NB * SPATIAL)      // 524288 per scale volume
#define NS       3
#define ROWS     16                  // W-rows per block in kernel A
#define ZT_PLANE 4096                // (d,h) plane in f4 units, per (s,b,w4)
#define DT       8                   // d-tile in kernel B
#define DTH      (DT + 6)            // with +-3 halo

typedef float f4 __attribute__((ext_vector_type(4)));

// -------------------------------------------------------------------------
// A: channel reduction + W box-sum, fused; writes TRANSPOSED zT[s][b][w4][d][h].
// Block = 256 threads = 16 rows x 16 lanes (each lane owns a float4 of W).
// x is read once per replay — PLAIN loads so x stays resident in the 256 MB
// Infinity Cache across graph replays (nt loads forced every replay to HBM
// at ~4.3 TB/s; L3 hits are much faster).  unroll 16 -> 16 loads in flight.
// -------------------------------------------------------------------------
__global__ __launch_bounds__(256) void kA(
        const float* __restrict__ x,
        const float* __restrict__ fw,
        float* __restrict__ zt) {
    __shared__ float sw[NS * CH];
    __shared__ f4 tile[NS][ROWS][16];        // 12 KB
    const int tid = threadIdx.x;
    if (tid < NS * CH) sw[tid] = fw[tid];
    __syncthreads();

    const int lr  = tid >> 4;                // row in block, 0..15
    const int lw  = tid & 15;                // float4 index along W, 0..15
    const int row = blockIdx.x * ROWS + lr;  // b*4096 + d*64 + h
    const int b   = row >> 12;
    const int dh  = row & 4095;              // d*64 + h

    const f4* xp = (const f4*)x
        + (size_t)b * CH * (SPATIAL / 4)
        + (size_t)dh * 16 + lw;

    f4 a0 = {0,0,0,0}, a1 = {0,0,0,0}, a2 = {0,0,0,0};
    #pragma unroll 16
    for (int c = 0; c < CH; ++c) {
        f4 v = xp[(size_t)c * (SPATIAL / 4)];
        a0 += sw[c] * v;
        a1 += sw[CH + c] * v;
        a2 += sw[2 * CH + c] * v;
    }
    tile[0][lr][lw] = a0;
    tile[1][lr][lw] = a1;
    tile[2][lr][lw] = a2;
    __syncthreads();

    f4* zt4 = (f4*)zt;
    const f4 zero = {0,0,0,0};
    #pragma unroll
    for (int s = 0; s < NS; ++s) {
        // 12-float window around this lane's 4 outputs; zero past row ends
        // == reference zero padding (count_include_pad).
        f4 m1 = (lw > 0)  ? tile[s][lr][lw - 1] : zero;
        f4 m0 = tile[s][lr][lw];
        f4 p1 = (lw < 15) ? tile[s][lr][lw + 1] : zero;
        float f[12] = {m1.x, m1.y, m1.z, m1.w,
                       m0.x, m0.y, m0.z, m0.w,
                       p1.x, p1.y, p1.z, p1.w};
        const int p = s + 1;
        f4 r;
        #pragma unroll
        for (int j = 0; j < 4; ++j) {
            float acc = 0.f;
            #pragma unroll
            for (int i = -3; i <= 3; ++i)
                if (i >= -p && i <= p) acc += f[4 + j + i];
            r[j] = acc;
        }
        // transposed store: zT[s][b][lw][d][h]  (64B-granule groups per wave)
        zt4[((size_t)(s * NB + b) * 16 + lw) * ZT_PLANE + dh] = r;
    }
}

// -------------------------------------------------------------------------
// B: fused H box-sum + D box-sum + 1/k^3 + cross-scale sum + bias + sigmoid.
// Block = (b, w4, d0-tile): loads zT tile (3 scales x 14 d x 64 h f4, 43 KB)
// with fully-contiguous reads (L2/L3-resident), H-pools in place (regs
// across a barrier), D-pools from LDS and writes the final output.
// -------------------------------------------------------------------------
__global__ __launch_bounds__(256) void kB(
        const float* __restrict__ zt,
        const float* __restrict__ fb,
        float* __restrict__ out) {
    __shared__ f4 tile[NS][DTH][DIM];        // 2688 f4 = 43 KB
    const int tid = threadIdx.x;
    const int bid = blockIdx.x;              // 2*16*8 = 256 blocks
    const int w4  = bid & 15;
    const int d0  = ((bid >> 4) & 7) * DT;
    const int b   = bid >> 7;

    const f4* zt4 = (const f4*)zt;
    #pragma unroll
    for (int s = 0; s < NS; ++s) {
        const f4* src = zt4 + ((size_t)(s * NB + b) * 16 + w4) * ZT_PLANE;
        #pragma unroll
        for (int t = 0; t < (DTH * DIM + 255) / 256; ++t) {
            int i = tid + t * 256;
            if (i < DTH * DIM) {
                int dd = i >> 6, h = i & 63;
                int gd = d0 - 3 + dd;
                f4 v = {0,0,0,0};
                if (gd >= 0 && gd < DIM) v = src[gd * 64 + h];
                tile[s][dd][h] = v;          // zero-filled halo == zero padding
            }
        }
    }
    __syncthreads();

    // H-pool in place: compute all windows into regs, barrier, write back.
    const int NITEM = NS * DTH * DIM;        // 2688
    f4 acc[11];                              // fixed-trip unrolled -> stays in VGPRs
    #pragma unroll
    for (int t = 0; t < 11; ++t) {
        int j = tid + t * 256;
        f4 a = {0,0,0,0};
        if (j < NITEM) {
            int s   = j / (DTH * DIM);
            int rem = j - s * (DTH * DIM);
            int dd  = rem >> 6, h = rem & 63;
            int p   = s + 1;
            int lo  = h - p; if (lo < 0)  lo = 0;
            int hi  = h + p; if (hi > 63) hi = 63;
            for (int hh = lo; hh <= hi; ++hh) a += tile[s][dd][hh];
        }
        acc[t] = a;
    }
    __syncthreads();
    #pragma unroll
    for (int t = 0; t < 11; ++t) {
        int j = tid + t * 256;
        if (j < NITEM) {
            int s   = j / (DTH * DIM);
            int rem = j - s * (DTH * DIM);
            tile[s][rem >> 6][rem & 63] = acc[t];
        }
    }
    __syncthreads();

    // D-pool + combine scales + bias + sigmoid -> final output.
    const float inv[NS] = {1.f / 27.f, 1.f / 125.f, 1.f / 343.f};
    const float bias = fb[0];
    f4* out4 = (f4*)out;
    #pragma unroll
    for (int t = 0; t < DT * DIM / 256; ++t) {   // 2 iters
        int j   = tid + t * 256;
        int ddp = j >> 6, h = j & 63;
        int d   = d0 + ddp;
        f4 a2 = {bias, bias, bias, bias};
        #pragma unroll
        for (int s = 0; s < NS; ++s) {
            int p = s + 1;
            f4 a = {0,0,0,0};
            for (int i = -3; i <= 3; ++i)        // halo rows already zero
                if (i >= -p && i <= p) a += tile[s][ddp + 3 + i][h];
            a2 += a * inv[s];
        }
        f4 r;
        #pragma unroll
        for (int jj = 0; jj < 4; ++jj) r[jj] = 1.f / (1.f + __expf(-a2[jj]));
        __builtin_nontemporal_store(r,
            &out4[(size_t)b * (SPATIAL / 4) + (size_t)d * 1024 + h * 16 + w4]);
    }
}

// -------------------------------------------------------------------------
extern "C" void kernel_launch(void* const* d_in, const int* in_sizes, int n_in,
                              void* d_out, int out_size, void* d_ws, size_t ws_size,
                              hipStream_t stream) {
    const float* x  = (const float*)d_in[0];   // (2, 48, 64, 64, 64) f32
    const float* fw = (const float*)d_in[1];   // (1, 144) f32
    const float* fb = (const float*)d_in[2];   // (1,) f32
    float* out = (float*)d_out;                // (2, 1, 64, 64, 64) f32

    float* zt = (float*)d_ws;                  // 3*VOL floats = 6.29 MB

    // A: channel mix + W box-sum -> zT (transposed)
    kA<<<(NB * DIM * DIM * DIM / ROWS) / 64, 256, 0, stream>>>(x, fw, zt);
    // B: H-pool + D-pool + scale + bias + sigmoid -> out
    kB<<<NB * 16 * (DIM / DT), 256, 0, stream>>>(zt, fb, out);
}

// Round 6
// 33.245 us; speedup vs baseline: 1.0009x; 1.0009x over previous
//
#include <hip/hip_runtime.h>
#include <math.h>

// Problem geometry (fixed by the reference setup)
#define CH       48
#define DIM      64
#define SPATIAL  (DIM * DIM * DIM)   // 262144 per (b, c)
#define NB       2
#define VOL      (NB * SPATIAL)      // 524288 per scale volume
#define NS       3
#define CSLAB    (SPATIAL / 4)       // 65536 f4 per (b,c) slab

// kernel A decomposition: 4 rows x 16 lw x 4 channel-groups = 256 threads
#define ROWS     4
#define CG       4                   // channel groups per block
#define CPG      (CH / CG)           // 12 channels per group

// kernel B decomposition
#define ZT_PLANE 4096                // (d,h) plane in f4 units, per (s,b,w4)
#define DT       4                   // d-tile
#define DTH      (DT + 6)            // with +-3 halo
#define NITEM    (NS * DTH * DIM)    // 1920 tile entries

typedef float f4 __attribute__((ext_vector_type(4)));

// -------------------------------------------------------------------------
// A: channel reduction + W box-sum -> zT[s][b][w4][d][h] (transposed).
// 2048 blocks (8/CU, ~24 waves/CU resident): each wave owns 12 channels of
// 4 rows; partials combined through LDS, then W-pool + transposed store.
// x is read exactly once (100.7 MB), fully coalesced 1KB/wave/channel.
// -------------------------------------------------------------------------
__global__ __launch_bounds__(256) void kA(
        const float* __restrict__ x,
        const float* __restrict__ fw,
        float* __restrict__ zt) {
    __shared__ float sw[NS * CH];
    __shared__ f4 part[CG][NS][ROWS][16];    // 768 f4 = 12 KB
    __shared__ f4 red[NS][ROWS][16];         // 192 f4 = 3 KB
    const int tid = threadIdx.x;
    if (tid < NS * CH) sw[tid] = fw[tid];
    __syncthreads();

    const int lw   = tid & 15;               // f4 index along W
    const int lr   = (tid >> 4) & 3;         // row within block
    const int cg   = tid >> 6;               // channel group == wave id
    const int row0 = blockIdx.x * ROWS;      // b*4096 + d*64 + h
    const int b    = row0 >> 12;
    const int dh   = (row0 & 4095) + lr;     // d*64 + h

    const f4* xp = (const f4*)x
        + (size_t)(b * CH + cg * CPG) * CSLAB
        + (size_t)dh * 16 + lw;

    f4 a0 = {0,0,0,0}, a1 = {0,0,0,0}, a2 = {0,0,0,0};
    #pragma unroll
    for (int c = 0; c < CPG; ++c) {
        f4 v = __builtin_nontemporal_load(&xp[(size_t)c * CSLAB]);
        const int cc = cg * CPG + c;
        a0 += sw[cc] * v;
        a1 += sw[CH + cc] * v;
        a2 += sw[2 * CH + cc] * v;
    }
    part[cg][0][lr][lw] = a0;
    part[cg][1][lr][lw] = a1;
    part[cg][2][lr][lw] = a2;
    __syncthreads();

    const int s = tid >> 6;                  // reuse lr/lw for tid<192
    if (tid < 192) {
        red[s][lr][lw] = part[0][s][lr][lw] + part[1][s][lr][lw]
                       + part[2][s][lr][lw] + part[3][s][lr][lw];
    }
    __syncthreads();
    if (tid < 192) {
        const f4 zero = {0,0,0,0};
        // 12-float window around this lane's 4 outputs; zero past row ends
        // == reference zero padding (count_include_pad).
        f4 m1 = (lw > 0)  ? red[s][lr][lw - 1] : zero;
        f4 m0 = red[s][lr][lw];
        f4 p1 = (lw < 15) ? red[s][lr][lw + 1] : zero;
        float f[12] = {m1.x, m1.y, m1.z, m1.w,
                       m0.x, m0.y, m0.z, m0.w,
                       p1.x, p1.y, p1.z, p1.w};
        const int p = s + 1;
        f4 r;
        #pragma unroll
        for (int j = 0; j < 4; ++j) {
            float acc = 0.f;
            #pragma unroll
            for (int i = -3; i <= 3; ++i)
                if (i >= -p && i <= p) acc += f[4 + j + i];
            r[j] = acc;
        }
        // transposed store: zT[s][b][lw][d][h]
        ((f4*)zt)[((size_t)(s * NB + b) * 16 + lw) * ZT_PLANE + dh] = r;
    }
}

// -------------------------------------------------------------------------
// B: fused H box-sum + D box-sum + 1/k^3 + cross-scale sum + bias + sigmoid.
// 512 blocks (2/CU): block = (b, w4, d-tile of 4). Loads zT tile
// (3 scales x 10 d x 64 h f4, 30 KB) fully contiguous, H-pools in place
// (regs across a barrier), D-pools from LDS, writes final output.
// -------------------------------------------------------------------------
__global__ __launch_bounds__(256) void kB(
        const float* __restrict__ zt,
        const float* __restrict__ fb,
        float* __restrict__ out) {
    __shared__ f4 tile[NS][DTH][DIM];        // 1920 f4 = 30 KB
    const int tid = threadIdx.x;
    const int bid = blockIdx.x;              // 2*16*16 = 512 blocks
    const int w4  = bid & 15;
    const int d0  = ((bid >> 4) & 15) * DT;
    const int b   = bid >> 8;

    const f4* zt4 = (const f4*)zt;
    #pragma unroll
    for (int s = 0; s < NS; ++s) {
        const f4* src = zt4 + ((size_t)(s * NB + b) * 16 + w4) * ZT_PLANE;
        #pragma unroll
        for (int t = 0; t < (DTH * DIM + 255) / 256; ++t) {  // 3 iters (last partial)
            int i = tid + t * 256;
            if (i < DTH * DIM) {
                int dd = i >> 6, h = i & 63;
                int gd = d0 - 3 + dd;
                f4 v = {0,0,0,0};
                if (gd >= 0 && gd < DIM) v = src[gd * 64 + h];
                tile[s][dd][h] = v;          // zero-filled halo == zero padding
            }
        }
    }
    __syncthreads();

    // H-pool in place: compute all windows into regs, barrier, write back.
    f4 acc[(NITEM + 255) / 256];             // 8, fixed-trip -> stays in VGPRs
    #pragma unroll
    for (int t = 0; t < (NITEM + 255) / 256; ++t) {
        int j = tid + t * 256;
        f4 a = {0,0,0,0};
        if (j < NITEM) {
            int s   = j / (DTH * DIM);
            int rem = j - s * (DTH * DIM);
            int dd  = rem >> 6, h = rem & 63;
            int p   = s + 1;
            int lo  = h - p; if (lo < 0)  lo = 0;
            int hi  = h + p; if (hi > 63) hi = 63;
            for (int hh = lo; hh <= hi; ++hh) a += tile[s][dd][hh];
        }
        acc[t] = a;
    }
    __syncthreads();
    #pragma unroll
    for (int t = 0; t < (NITEM + 255) / 256; ++t) {
        int j = tid + t * 256;
        if (j < NITEM) {
            int s   = j / (DTH * DIM);
            int rem = j - s * (DTH * DIM);
            tile[s][rem >> 6][rem & 63] = acc[t];
        }
    }
    __syncthreads();

    // D-pool + combine scales + bias + sigmoid -> final output (256 outputs).
    const float inv[NS] = {1.f / 27.f, 1.f / 125.f, 1.f / 343.f};
    const float bias = fb[0];
    const int ddp = tid >> 6, h = tid & 63;
    const int d   = d0 + ddp;
    f4 a2 = {bias, bias, bias, bias};
    #pragma unroll
    for (int s = 0; s < NS; ++s) {
        int p = s + 1;
        f4 a = {0,0,0,0};
        #pragma unroll
        for (int i = -3; i <= 3; ++i)        // halo rows already zero
            if (i >= -p && i <= p) a += tile[s][ddp + 3 + i][h];
        a2 += a * inv[s];
    }
    f4 r;
    #pragma unroll
    for (int jj = 0; jj < 4; ++jj) r[jj] = 1.f / (1.f + __expf(-a2[jj]));
    __builtin_nontemporal_store(r,
        &((f4*)out)[(size_t)b * (SPATIAL / 4) + (size_t)d * 1024 + h * 16 + w4]);
}

// -------------------------------------------------------------------------
extern "C" void kernel_launch(void* const* d_in, const int* in_sizes, int n_in,
                              void* d_out, int out_size, void* d_ws, size_t ws_size,
                              hipStream_t stream) {
    const float* x  = (const float*)d_in[0];   // (2, 48, 64, 64, 64) f32
    const float* fw = (const float*)d_in[1];   // (1, 144) f32
    const float* fb = (const float*)d_in[2];   // (1,) f32
    float* out = (float*)d_out;                // (2, 1, 64, 64, 64) f32

    float* zt = (float*)d_ws;                  // 3*VOL floats = 6.29 MB

    // A: channel mix + W box-sum -> zT (transposed), 2048 blocks
    kA<<<NB * DIM * DIM * DIM / DIM / ROWS * DIM / DIM, 256, 0, stream>>>(x, fw, zt);
    // (grid = NB*4096/ROWS = 2048)
    // B: H-pool + D-pool + scale + bias + sigmoid -> out, 512 blocks
    kB<<<NB * 16 * (DIM / DT), 256, 0, stream>>>(zt, fb, out);
}